// Round 11
// baseline (339.631 us; speedup 1.0000x reference)
//
#include <hip/hip_runtime.h>
#include <hip/hip_bf16.h>

#define NRBF 20
#define KAUG 32   // 20 rbf + env(bias row) + zeros; 64B rows for aligned vector loads

typedef __attribute__((ext_vector_type(8))) short short8;
typedef __attribute__((ext_vector_type(4))) float float4v;
typedef __attribute__((ext_vector_type(2))) _Float16 half2v;
typedef __attribute__((ext_vector_type(8))) _Float16 half8v;
typedef unsigned short ushort_t;

union H8 { half8v v8; half2v v2[4]; };

__device__ __forceinline__ float bf2f(ushort_t u) {
    return __uint_as_float(((unsigned)u) << 16);
}
__device__ __forceinline__ ushort_t f2bf(float f) {
    unsigned u = __float_as_uint(f);
    u += 0x7FFF + ((u >> 16) & 1);   // round-to-nearest-even
    return (ushort_t)(u >> 16);
}
__device__ __forceinline__ float ldin(const void* p, size_t idx, int isbf) {
    return isbf ? bf2f(((const ushort_t*)p)[idx]) : ((const float*)p)[idx];
}
__device__ __forceinline__ void stout(void* p, size_t idx, float v, int isbf) {
    if (isbf) ((ushort_t*)p)[idx] = f2bf(v);
    else      ((float*)p)[idx] = v;
}
__device__ __forceinline__ float dot2(half2v a, half2v b, float c) {
#if __has_builtin(__builtin_amdgcn_fdot2)
    return __builtin_amdgcn_fdot2(a, b, c, false);
#else
    return c + (float)a.x * (float)b.x + (float)a.y * (float)b.y;
#endif
}

// ---------------- dtype detect + deg zero (fused) ----------------
__global__ void detect_kernel(const void* __restrict__ xyz, int* __restrict__ flag,
                              int* __restrict__ deg, int N) {
    int idx = blockIdx.x * blockDim.x + threadIdx.x;
    if (idx < N) deg[idx] = 0;
    if (blockIdx.x == 0 && threadIdx.x < 64) {
        const ushort_t* u = (const ushort_t*)xyz;
        unsigned e0 = (u[2 * threadIdx.x] >> 7) & 0xFF;
        unsigned long long bad = __ballot(e0 >= 0x90);
        if (threadIdx.x == 0) *flag = (__popcll(bad) > 2) ? 0 : 1;  // 1=bf16, 0=f32
    }
}

// ---------------- prelude: deg count + s init + weight prep ----------------
// B1 frags [l][ks4][nt8][lane64][8]; B2 frags [l][ks4][nt24][lane64][8];
// WrT f16 [l][col384][KAUG]: k<20 = Wr[l][k][col], k==20 = br[l][col], else 0.
__global__ void prelude_kernel(const void* __restrict__ xyz, const int* __restrict__ nbr,
                               const void* __restrict__ cg_s,
                               const void* __restrict__ W1, const void* __restrict__ W2,
                               const void* __restrict__ Wr, const void* __restrict__ br,
                               float* __restrict__ s_acc, ushort_t* __restrict__ s_hi,
                               ushort_t* __restrict__ s_lo, int* __restrict__ deg,
                               ushort_t* __restrict__ B1hi, ushort_t* __restrict__ B1lo,
                               ushort_t* __restrict__ B2hi, ushort_t* __restrict__ B2lo,
                               _Float16* __restrict__ WrT,
                               int N128, int E, const int* __restrict__ flagp) {
    int isbf = *flagp;
    int idx = blockIdx.x * blockDim.x + threadIdx.x;
    if (idx < E) {
        int i = nbr[2 * idx], j = nbr[2 * idx + 1];
        float dx = ldin(xyz, 3 * j,     isbf) - ldin(xyz, 3 * i,     isbf);
        float dy = ldin(xyz, 3 * j + 1, isbf) - ldin(xyz, 3 * i + 1, isbf);
        float dz = ldin(xyz, 3 * j + 2, isbf) - ldin(xyz, 3 * i + 2, isbf);
        float dist = sqrtf(dx * dx + dy * dy + dz * dz + 3e-15f);
        if (dist < 5.0f) atomicAdd(&deg[i], 1);
    }
    if (idx < N128) {
        float v = ldin(cg_s, idx, isbf);
        s_acc[idx] = v;
        ushort_t hi = f2bf(v);
        s_hi[idx] = hi;
        s_lo[idx] = f2bf(v - bf2f(hi));
    }
    const int NW1 = 3 * 4 * 8 * 64;
    const int NW2 = 3 * 4 * 24 * 64;
    const int NWT = 3 * 384;
    if (idx < NW1) {
        int lane = idx & 63;
        int t = idx >> 6;
        int nt = t % 8; t /= 8;
        int ks = t % 4; int l = t / 4;
        int n = lane & 15, quad = lane >> 4;
        int col = nt * 16 + n;
        size_t base = (size_t)l * 128 * 128;
        size_t fo = (size_t)idx * 8;
        #pragma unroll
        for (int j = 0; j < 8; j++) {
            int k = ks * 32 + quad * 8 + j;
            float v = ldin(W1, base + (size_t)k * 128 + col, isbf);
            ushort_t hi = f2bf(v);
            B1hi[fo + j] = hi;
            B1lo[fo + j] = f2bf(v - bf2f(hi));
        }
    } else if (idx < NW1 + NW2) {
        int i2 = idx - NW1;
        int lane = i2 & 63;
        int t = i2 >> 6;
        int nt = t % 24; t /= 24;
        int ks = t % 4; int l = t / 4;
        int n = lane & 15, quad = lane >> 4;
        int col = nt * 16 + n;
        size_t base = (size_t)l * 128 * 384;
        size_t fo = (size_t)i2 * 8;
        #pragma unroll
        for (int j = 0; j < 8; j++) {
            int k = ks * 32 + quad * 8 + j;
            float v = ldin(W2, base + (size_t)k * 384 + col, isbf);
            ushort_t hi = f2bf(v);
            B2hi[fo + j] = hi;
            B2lo[fo + j] = f2bf(v - bf2f(hi));
        }
    } else if (idx < NW1 + NW2 + NWT) {
        int i2 = idx - NW1 - NW2;
        int l = i2 / 384, col = i2 % 384;
        _Float16* wt = WrT + ((size_t)l * 384 + col) * KAUG;
        #pragma unroll
        for (int k = 0; k < KAUG; k++) {
            float v = 0.f;
            if (k < NRBF) v = ldin(Wr, ((size_t)l * NRBF + k) * 384 + col, isbf);
            else if (k == NRBF) v = ldin(br, (size_t)l * 384 + col, isbf);
            wt[k] = (_Float16)v;
        }
    }
}

// ---------------- scan: rowptr from deg; deg becomes cursor ----------------
__global__ void scan_kernel(int* __restrict__ deg, int* __restrict__ rowptr, int N) {
    __shared__ int part[256];
    int t = threadIdx.x;
    int chunk = (N + 255) / 256;
    int lo = t * chunk, hi = min(lo + chunk, N);
    int s = 0;
    for (int i = lo; i < hi; i++) s += deg[i];
    part[t] = s;
    __syncthreads();
    for (int off = 1; off < 256; off <<= 1) {
        int v = (t >= off) ? part[t - off] : 0;
        __syncthreads();
        if (t >= off) part[t] += v;
        __syncthreads();
    }
    int base = (t == 0) ? 0 : part[t - 1];
    for (int i = lo; i < hi; i++) {
        rowptr[i] = base;
        int d = deg[i];
        deg[i] = base;
        base += d;
    }
    if (t == 0) rowptr[N] = part[255];
}

// ---------------- pack: geometry + CSR scatter (pos-ordered) ----------------
// jlist[pos]=j, upos[pos]=(ux,uy,uz,env), rbfh f16 [pos][KAUG]: k<20 = env*rbf_k,
// k==20 = env (bias row), k in 21..23 = 0 (only halves 0..23 are ever loaded).
__global__ void pack_kernel(const void* __restrict__ xyz, const int* __restrict__ nbr,
                            int* __restrict__ cursor, int* __restrict__ jlist,
                            float4* __restrict__ upos, _Float16* __restrict__ rbfh,
                            int E, const int* __restrict__ flagp) {
    int isbf = *flagp;
    int e = blockIdx.x * blockDim.x + threadIdx.x;
    if (e >= E) return;
    int i = nbr[2 * e], j = nbr[2 * e + 1];
    float dx = ldin(xyz, 3 * j,     isbf) - ldin(xyz, 3 * i,     isbf);
    float dy = ldin(xyz, 3 * j + 1, isbf) - ldin(xyz, 3 * i + 1, isbf);
    float dz = ldin(xyz, 3 * j + 2, isbf) - ldin(xyz, 3 * i + 2, isbf);
    float dist = sqrtf(dx * dx + dy * dy + dz * dz + 3e-15f);
    if (!(dist < 5.0f)) return;
    constexpr float PI = 3.14159265358979323846f;
    float ev = 0.5f * (cosf(PI * dist * 0.2f) + 1.0f);
    int pos = atomicAdd(&cursor[i], 1);
    jlist[pos] = j;
    float inv = 1.0f / dist;
    upos[pos] = make_float4(dx * inv, dy * inv, dz * inv, ev);
    constexpr double EM5 = 0.006737946999085467;  // exp(-5)
    constexpr float MU0 = (float)EM5;
    constexpr float DMU = (float)((1.0 - EM5) / 19.0);
    constexpr float BETA = (float)(1.0 / ((0.1 * (1.0 - EM5)) * (0.1 * (1.0 - EM5))));
    float ed = expf(-dist);
    _Float16* rp = rbfh + (size_t)pos * KAUG;
    #pragma unroll
    for (int k = 0; k < NRBF; k++) {
        float dmu = ed - (MU0 + k * DMU);
        rp[k] = (_Float16)(ev * expf(-BETA * dmu * dmu));
    }
    rp[NRBF] = (_Float16)ev;
    #pragma unroll
    for (int k = NRBF + 1; k < 24; k++) rp[k] = (_Float16)0.f;
}

// ---------------- MFMA GEMM, 1D swizzled grid for A-locality ----------------
template <int ACT, int OUTMODE, int NTILES>
__global__ __launch_bounds__(256) void mfma_gemm(
    const ushort_t* __restrict__ Ahi, const ushort_t* __restrict__ Alo,
    const ushort_t* __restrict__ Bhi, const ushort_t* __restrict__ Blo,
    const void* __restrict__ bias, size_t biasoff,
    ushort_t* __restrict__ out_hi, ushort_t* __restrict__ out_lo,
    int M, const int* __restrict__ flagp) {
    constexpr int Ncols = NTILES * 16;
    int isbf = *flagp;
    int nt = blockIdx.x % NTILES;
    int bx = blockIdx.x / NTILES;
    int tid = threadIdx.x;
    int wave = tid >> 6, lane = tid & 63;
    int m = lane & 15, quad = lane >> 4;
    int brow = bx * 64 + wave * 16;
    int row = brow + m;
    float4v acc = {};
    short8 zero8 = {};
    #pragma unroll
    for (int ks = 0; ks < 4; ks++) {
        short8 ah = zero8, al = zero8;
        if (row < M) {
            size_t ao = (size_t)row * 128 + ks * 32 + quad * 8;
            ah = *reinterpret_cast<const short8*>(Ahi + ao);
            al = *reinterpret_cast<const short8*>(Alo + ao);
        }
        size_t fo = (((size_t)ks * NTILES + nt) * 64 + lane) * 8;
        short8 bh = *reinterpret_cast<const short8*>(Bhi + fo);
        acc = __builtin_amdgcn_mfma_f32_16x16x32_bf16(ah, bh, acc, 0, 0, 0);
        acc = __builtin_amdgcn_mfma_f32_16x16x32_bf16(al, bh, acc, 0, 0, 0);
        if (!isbf) {
            short8 bl = *reinterpret_cast<const short8*>(Blo + fo);
            acc = __builtin_amdgcn_mfma_f32_16x16x32_bf16(ah, bl, acc, 0, 0, 0);
        }
    }
    int col = nt * 16 + m;
    float bv = ldin(bias, biasoff + col, isbf);
    #pragma unroll
    for (int r = 0; r < 4; r++) {
        int orow = brow + quad * 4 + r;
        if (orow >= M) continue;
        float x = acc[r] + bv;
        if (ACT) x = x / (1.0f + expf(-x));  // silu
        size_t oo = (size_t)orow * Ncols + col;
        ushort_t h = f2bf(x);
        out_hi[oo] = h;
        if (OUTMODE == 0) out_lo[oo] = f2bf(x - bf2f(h));
    }
}

// ---------------- node gather kernel: 1-deep software pipeline ----------------
// One block per node, 128 threads; thread tt owns features {tt, 128+tt, 256+tt}.
// While computing edge k, loads for edge k+1 are in flight.
template <int L0, int LAST>
__global__ __launch_bounds__(128, 4) void node_kernel(
    const int* __restrict__ rowptr, const int* __restrict__ jlist,
    const float4* __restrict__ upos, const _Float16* __restrict__ rbfh,
    const _Float16* __restrict__ WrT,
    const ushort_t* __restrict__ phi,
    const float* __restrict__ v_old, const ushort_t* __restrict__ vh_old,
    float* __restrict__ s_acc, ushort_t* __restrict__ s_hi, ushort_t* __restrict__ s_lo,
    float* __restrict__ v_new, ushort_t* __restrict__ vh_new,
    void* __restrict__ out, int N, const int* __restrict__ flagp) {
    int isbf = *flagp;
    int tt = threadIdx.x;
    int node = blockIdx.x;

    // hoist this thread's 3 WrT columns: 3 half8 each, unpacked as half2[12]
    H8 wcA[3], wcB[3], wcC[3];
    {
        const half8v* w0p = (const half8v*)(WrT + (size_t)tt * KAUG);
        const half8v* w1p = (const half8v*)(WrT + (size_t)(tt + 128) * KAUG);
        const half8v* w2p = (const half8v*)(WrT + (size_t)(tt + 256) * KAUG);
        #pragma unroll
        for (int q = 0; q < 3; q++) {
            wcA[q].v8 = w0p[q]; wcB[q].v8 = w1p[q]; wcC[q].v8 = w2p[q];
        }
    }
    int start = __builtin_amdgcn_readfirstlane(rowptr[node]);
    int end   = __builtin_amdgcn_readfirstlane(rowptr[node + 1]);

    float dsv = 0.f, ax = 0.f, ay = 0.f, az = 0.f;
    if (start < end) {
        // prologue: full loads for edge 'start'
        int j_c = jlist[start];
        float4 u_c = upos[start];
        const half8v* rp = (const half8v*)(rbfh + (size_t)start * KAUG);
        H8 r0, r1, r2;
        r0.v8 = rp[0]; r1.v8 = rp[1]; r2.v8 = rp[2];
        size_t jb = (size_t)j_c * 384;
        ushort_t p0 = phi[jb + tt], p1 = phi[jb + 128 + tt], p2 = phi[jb + 256 + tt];
        ushort_t v0 = 0, v1 = 0, v2 = 0;
        if (!L0) {
            const ushort_t* vj = &vh_old[jb + (size_t)tt * 3];
            v0 = vj[0]; v1 = vj[1]; v2 = vj[2];
        }
        for (int k = start; k < end; k++) {
            // issue next edge's loads (clamped at tail; redundant but harmless)
            int kn = (k + 1 < end) ? k + 1 : k;
            int j_n = jlist[kn];
            float4 u_n = upos[kn];
            const half8v* rpn = (const half8v*)(rbfh + (size_t)kn * KAUG);
            H8 n0, n1, n2;
            n0.v8 = rpn[0]; n1.v8 = rpn[1]; n2.v8 = rpn[2];
            size_t jbn = (size_t)j_n * 384;
            ushort_t q0 = phi[jbn + tt], q1 = phi[jbn + 128 + tt], q2 = phi[jbn + 256 + tt];
            ushort_t x0 = 0, x1 = 0, x2 = 0;
            if (!L0) {
                const ushort_t* vjn = &vh_old[jbn + (size_t)tt * 3];
                x0 = vjn[0]; x1 = vjn[1]; x2 = vjn[2];
            }
            // compute with current edge
            float w0 = 0.f, w1 = 0.f, w2 = 0.f;
            #pragma unroll
            for (int q = 0; q < 3; q++) {
                const H8& rq = (q == 0) ? r0 : (q == 1) ? r1 : r2;
                #pragma unroll
                for (int p = 0; p < 4; p++) {
                    half2v pr = rq.v2[p];
                    w0 = dot2(pr, wcA[q].v2[p], w0);
                    w1 = dot2(pr, wcB[q].v2[p], w1);
                    w2 = dot2(pr, wcC[q].v2[p], w2);
                }
            }
            dsv += bf2f(p0) * w0;
            float gv = bf2f(p1) * w1;
            float gu = bf2f(p2) * w2;
            if (L0) {
                ax += gu * u_c.x; ay += gu * u_c.y; az += gu * u_c.z;
            } else {
                ax += gu * u_c.x + gv * bf2f(v0);
                ay += gu * u_c.y + gv * bf2f(v1);
                az += gu * u_c.z + gv * bf2f(v2);
            }
            // rotate pipeline registers
            u_c = u_n; r0 = n0; r1 = n1; r2 = n2;
            p0 = q0; p1 = q1; p2 = q2;
            v0 = x0; v1 = x1; v2 = x2;
        }
    }
    size_t so = (size_t)node * 128 + tt;
    float snew = s_acc[so] + dsv;
    size_t ib = (size_t)node * 384 + (size_t)tt * 3;
    float vx = L0 ? ax : v_old[ib]     + ax;
    float vy = L0 ? ay : v_old[ib + 1] + ay;
    float vz = L0 ? az : v_old[ib + 2] + az;
    if (LAST) {
        stout(out, so, snew, isbf);
        size_t ob = (size_t)N * 128 + ib;
        stout(out, ob,     vx, isbf);
        stout(out, ob + 1, vy, isbf);
        stout(out, ob + 2, vz, isbf);
    } else {
        s_acc[so] = snew;
        ushort_t hi = f2bf(snew);
        s_hi[so] = hi;
        s_lo[so] = f2bf(snew - bf2f(hi));
        v_new[ib] = vx; v_new[ib + 1] = vy; v_new[ib + 2] = vz;
        vh_new[ib]     = f2bf(vx);
        vh_new[ib + 1] = f2bf(vy);
        vh_new[ib + 2] = f2bf(vz);
    }
}

extern "C" void kernel_launch(void* const* d_in, const int* in_sizes, int n_in,
                              void* d_out, int out_size, void* d_ws, size_t ws_size,
                              hipStream_t stream) {
    const int N = in_sizes[0] / 3;
    const int E = in_sizes[1] / 2;
    const void* xyz  = d_in[0];
    const int*  nbr  = (const int*)d_in[1];
    const void* cg_s = d_in[2];
    const void* W1   = d_in[3];
    const void* b1   = d_in[4];
    const void* W2   = d_in[5];
    const void* b2   = d_in[6];
    const void* Wr   = d_in[7];
    const void* br   = d_in[8];

    size_t off = 0;
    auto alloc = [&](size_t bytes) -> char* {
        char* p = (char*)d_ws + off;
        off = (off + bytes + 63) & ~(size_t)63;
        return p;
    };
    int*       flag   = (int*)alloc(64);
    float*     s_acc  = (float*)alloc((size_t)N * 128 * 4);
    float*     vA     = (float*)alloc((size_t)N * 384 * 4);
    float*     vB     = (float*)alloc((size_t)N * 384 * 4);
    int*       rowptr = (int*)alloc((size_t)(N + 1) * 4);
    int*       deg    = (int*)alloc((size_t)N * 4);
    int*       jlist  = (int*)alloc((size_t)E * 4);
    float4*    upos   = (float4*)alloc((size_t)(E + 16) * 16);
    _Float16*  rbfh   = (_Float16*)alloc((size_t)(E + 16) * KAUG * 2);
    _Float16*  WrT    = (_Float16*)alloc((size_t)3 * 384 * KAUG * 2);
    ushort_t*  s_hi   = (ushort_t*)alloc((size_t)N * 128 * 2);
    ushort_t*  s_lo   = (ushort_t*)alloc((size_t)N * 128 * 2);
    ushort_t*  h_hi   = (ushort_t*)alloc((size_t)N * 128 * 2);
    ushort_t*  h_lo   = (ushort_t*)alloc((size_t)N * 128 * 2);
    ushort_t*  phi    = (ushort_t*)alloc((size_t)N * 384 * 2);
    ushort_t*  vhA    = (ushort_t*)alloc((size_t)N * 384 * 2);
    ushort_t*  vhB    = (ushort_t*)alloc((size_t)N * 384 * 2);
    ushort_t*  B1hi   = (ushort_t*)alloc((size_t)3 * 4 * 8 * 64 * 8 * 2);
    ushort_t*  B1lo   = (ushort_t*)alloc((size_t)3 * 4 * 8 * 64 * 8 * 2);
    ushort_t*  B2hi   = (ushort_t*)alloc((size_t)3 * 4 * 24 * 64 * 8 * 2);
    ushort_t*  B2lo   = (ushort_t*)alloc((size_t)3 * 4 * 24 * 64 * 8 * 2);

    detect_kernel<<<(N + 255) / 256, 256, 0, stream>>>(xyz, flag, deg, N);
    const int N128 = N * 128;
    const int pg = (max(E, N128) + 255) / 256;
    prelude_kernel<<<pg, 256, 0, stream>>>(xyz, nbr, cg_s, W1, W2, Wr, br,
                                           s_acc, s_hi, s_lo, deg,
                                           B1hi, B1lo, B2hi, B2lo, WrT,
                                           N128, E, flag);
    scan_kernel<<<1, 256, 0, stream>>>(deg, rowptr, N);
    pack_kernel<<<(E + 255) / 256, 256, 0, stream>>>(xyz, nbr, deg, jlist, upos,
                                                     rbfh, E, flag);

    const int gx = (N + 63) / 64;
    for (int l = 0; l < 3; l++) {
        mfma_gemm<1, 0, 8><<<gx * 8, 256, 0, stream>>>(
            s_hi, s_lo,
            B1hi + (size_t)l * 4 * 8 * 64 * 8, B1lo + (size_t)l * 4 * 8 * 64 * 8,
            b1, (size_t)l * 128, h_hi, h_lo, N, flag);
        mfma_gemm<0, 1, 24><<<gx * 24, 256, 0, stream>>>(
            h_hi, h_lo,
            B2hi + (size_t)l * 4 * 24 * 64 * 8, B2lo + (size_t)l * 4 * 24 * 64 * 8,
            b2, (size_t)l * 384, phi, (ushort_t*)nullptr, N, flag);
        const _Float16* wrt = WrT + (size_t)l * 384 * KAUG;
        if (l == 0) {
            node_kernel<1, 0><<<N, 128, 0, stream>>>(
                rowptr, jlist, upos, rbfh, wrt, phi,
                vA, vhA, s_acc, s_hi, s_lo, vA, vhA, d_out, N, flag);
        } else if (l == 1) {
            node_kernel<0, 0><<<N, 128, 0, stream>>>(
                rowptr, jlist, upos, rbfh, wrt, phi,
                vA, vhA, s_acc, s_hi, s_lo, vB, vhB, d_out, N, flag);
        } else {
            node_kernel<0, 1><<<N, 128, 0, stream>>>(
                rowptr, jlist, upos, rbfh, wrt, phi,
                vB, vhB, s_acc, s_hi, s_lo, vB, vhB, d_out, N, flag);
        }
    }
}